// Round 7
// baseline (632.107 us; speedup 1.0000x reference)
//
#include <hip/hip_runtime.h>
#include <stdint.h>

// RNN car-following, 256 sequential steps x 4096 vehicles; 8 veh/WG, 512 WGs,
// 4 waves (256 thr), 2 WG/CU.
// Round-7: K=4 STEP BLOCKING — one barrier per 4 steps (65 barriers total).
//   Chain (wave0) runs 4 full steps back-to-back in-wave: conv1 rows 11/12
//   (x-columns carried in ROLLING REGISTERS, zero Xcol reads), conv2 j9/j10
//   (old terms as early-issue MFMAs — accb LDS handoff deleted), jp3/jp4/jp5,
//   dense epilogue, state, output->obuf, new column via shfl broadcast.
//   Helpers produce next block's material (parity double-buffered, verified
//   non-aliasing with enlarged rings P=24+5, O2=20+5):
//     W1: r0->j0->jp0 for steps +4,+5   W3: same for steps +6,+7
//     W2: jp1/jp2 for 4 steps + lead prefetch + obuf flush of prev block.
//   jpacc dense [64][4] f32 (stride-4, conflict-free).

#define PAST 25

typedef __attribute__((ext_vector_type(8))) short bf16x8;
typedef __attribute__((ext_vector_type(4))) float f32x4;
typedef unsigned short u16x2 __attribute__((ext_vector_type(2)));
#define MFMA16 __builtin_amdgcn_mfma_f32_16x16x32_bf16

static __device__ __forceinline__ uint32_t f2bf(float f) {
  union { float f; uint32_t u; } x; x.f = f;
  return (x.u + 0x7FFFu + ((x.u >> 16) & 1u)) >> 16;
}
static __device__ __forceinline__ float bf2f(uint32_t b) {
  union { uint32_t u; float f; } x; x.u = b << 16; return x.f;
}
static __device__ __forceinline__ uint32_t pkbf(float lo, float hi) {
  return f2bf(lo) | (f2bf(hi) << 16);
}
static __device__ __forceinline__ f32x4 bcast4(float v) { f32x4 r = {v, v, v, v}; return r; }

static __device__ __forceinline__ uint32_t pkmax(uint32_t a, uint32_t b) {
#if __has_builtin(__builtin_elementwise_max)
  union U { uint32_t w; u16x2 v; } x, y; x.w = a; y.w = b;
  x.v = __builtin_elementwise_max(x.v, y.v);
  return x.w;
#else
  uint32_t al = a << 16, bl = b << 16;
  uint32_t lo = (al > bl ? al : bl) >> 16;
  uint32_t ah = a & 0xffff0000u, bh = b & 0xffff0000u;
  uint32_t hi = ah > bh ? ah : bh;
  return lo | hi;
#endif
}
static __device__ __forceinline__ uint4 maxq(uint4 a, uint4 b) {
  uint4 r; r.x = pkmax(a.x, b.x); r.y = pkmax(a.y, b.y);
  r.z = pkmax(a.z, b.z); r.w = pkmax(a.w, b.w); return r;
}
static __device__ __forceinline__ int w24(int x) {
  if (x >= 24) x -= 24; if (x >= 24) x -= 24; return x;
}
static __device__ __forceinline__ int w20(int x) {
  if (x >= 20) x -= 20; if (x >= 20) x -= 20; return x;
}

union FragU { bf16x8 v; uint16_t u[8]; uint4 q; };
struct Acc4 { f32x4 a[4]; };

// 2112 + 14848 + 25600 + 16384 + 512 + 512 = 59968 B (2 WG/CU -> 117 KB < 160)
struct __align__(16) SMem {
  uint32_t Xcol[8][33][2];     // x-column ring (u&31)
  uint16_t P[29 * 8 * 32];     // pooled conv1: ring 0..23 (g%24), r0-locals 24..27, row12 28
  uint16_t O2[25 * 8 * 64];    // out2: ring 0..19 (a%20), j0-locals 20..23, j10 24
  float jpacc[2][4][2][64][4]; // dense partials [par][step-in-block][W1|W2][lane][4]
  float2 leadsl[2][4][8];      // lead handoff [par][s][veh]
  float2 obuf[2][4][8];        // output buffer [par][s][veh]
};

__global__ __launch_bounds__(256, 2) void rnncf_kernel(
    const float* __restrict__ lead_states, const float* __restrict__ cur_states,
    const float* __restrict__ conv1_w, const float* __restrict__ conv1_b,
    const float* __restrict__ conv2_w, const float* __restrict__ conv2_b,
    const float* __restrict__ dense2_w, const float* __restrict__ dense2_b,
    const float* __restrict__ dense1_w, const float* __restrict__ dense1_b,
    float* __restrict__ out, int nt, int ntw) {
  __shared__ SMem sm;
  const int tid = threadIdx.x;
  const int lane = tid & 63;
  const int wid = tid >> 6;           // 0..3
  const int n = lane & 15;
  const int quad = lane >> 4;
  const int vbase = blockIdx.x * 8;

  // ---------------- phase 0: Xcol u=0..24 + state + weights ----------------
  if (tid < 200) {
    int v = tid & 7, u = tid >> 3;
    const float2 l = *(const float2*)(lead_states + ((size_t)(vbase + v) * ntw + u) * 2);
    const float2 c = *(const float2*)(cur_states + ((size_t)(vbase + v) * PAST + u) * 2);
    float x0 = (l.x - c.x) * 0.005f;
    uint32_t hi = f2bf(x0);
    uint32_t lo = f2bf(x0 - bf2f(hi));
    sm.Xcol[v][u][0] = hi | (f2bf(c.y * 0.025f) << 16);
    sm.Xcol[v][u][1] = f2bf(l.y * 0.025f) | (lo << 16);
  }
  float pos_s = 0.f, spd_s = 0.f;
  if (wid == 0 && lane < 8) {
    const float2 c = *(const float2*)(cur_states + ((size_t)(vbase + lane) * PAST + 24) * 2);
    pos_s = c.x * 0.005f; spd_s = c.y * 0.025f;
  }

  FragU B1[2];
#pragma unroll
  for (int ct = 0; ct < 2; ++ct)
#pragma unroll
    for (int jj = 0; jj < 8; ++jj) {
      int k = quad * 8 + jj;
      int dw = k & 3, cig = (k >> 2) & 3;
      float w = 0.f;
      if (k < 16 && dw < 3) {
        int ci = (cig == 3) ? 0 : cig;
        w = conv1_w[(dw * 3 + ci) * 32 + ct * 16 + n];
      }
      B1[ct].u[jj] = (uint16_t)f2bf(w);
    }
  FragU B2[3][4];
#pragma unroll
  for (int dw = 0; dw < 3; ++dw)
#pragma unroll
    for (int ct = 0; ct < 4; ++ct)
#pragma unroll
      for (int jj = 0; jj < 8; ++jj) {
        int kap = quad * 8 + jj;
        int ci = (kap & 1) * 16 + (kap >> 1);
        B2[dw][ct].u[jj] = (uint16_t)f2bf(conv2_w[(dw * 32 + ci) * 64 + ct * 16 + n]);
      }
  FragU Bd[12];
#pragma unroll
  for (int kt = 0; kt < 12; ++kt)
#pragma unroll
    for (int jj = 0; jj < 8; ++jj) {
      int flat = kt * 32 + quad * 8 + jj;
      int jp = flat >> 6, kap = flat & 63;
      int co = (kap & 3) * 16 + (kap >> 2);
      Bd[kt].u[jj] = (uint16_t)f2bf((n < 10) ? dense2_w[(jp * 64 + co) * 10 + n] : 0.f);
    }
  const float b1v0 = conv1_b[n], b1v1 = conv1_b[16 + n];
  float b2v[4];
#pragma unroll
  for (int ct = 0; ct < 4; ++ct) b2v[ct] = conv2_b[ct * 16 + n];
  f32x4 dbias; float w1r[4];
#pragma unroll
  for (int r = 0; r < 4; ++r) {
    int o = quad * 4 + r;
    dbias[r] = (o < 10) ? dense2_b[o] : 0.f;
    w1r[r] = (o < 10) ? dense1_w[o] : 0.f;
  }
  const float bd1v = dense1_b[0];

  // ---------------- helpers ----------------
  auto pIdx = [&](int s, int veh, int ch) { return ((s * 8 + veh) * 4 + ch) * 8; };
  auto oIdx = [&](int s, int veh, int ch) { return ((s * 8 + veh) * 8 + ch) * 8; };
  auto Xld = [&](int u) -> uint32_t { return sm.Xcol[n & 7][u & 31][quad & 1]; };

  auto mkfrag = [&](uint32_t d0, uint32_t d1, uint32_t d2) -> FragU {
    FragU a;
    a.q.x = __builtin_amdgcn_perm(d1, d0, 0x05040100u);
    a.q.y = d2 & 0xffffu;
    a.q.z = __builtin_amdgcn_perm(d1, d0, 0x07060302u);
    a.q.w = d2 >> 16;
    return a;
  };
  auto build_x = [&](int c, int padL, int padR) -> FragU {
    uint32_t d0 = padL ? 0u : Xld(c - 1);
    uint32_t d1 = Xld(c);
    uint32_t d2 = padR ? 0u : Xld(c + 1);
    return mkfrag(d0, d1, d2);
  };
  auto p_write = [&](int ds, float e0, float e1, int r) {
    int veh = quad * 4 + r;
    *(uint32_t*)&sm.P[pIdx(ds, veh, (n >> 2) ^ (veh & 3)) + (n & 3) * 2] = pkbf(e0, e1);
  };
  auto conv1_pair = [&](int cA, int pLA, int pRA, int cB, int pLB, int pRB, int ds) {
    FragU aA = build_x(cA, pLA, pRA);
    FragU aB = build_x(cB, pLB, pRB);
    f32x4 d0a = MFMA16(aA.v, B1[0].v, bcast4(b1v0), 0, 0, 0);
    f32x4 d0b = MFMA16(aB.v, B1[0].v, bcast4(b1v0), 0, 0, 0);
    f32x4 d1a = MFMA16(aA.v, B1[1].v, bcast4(b1v1), 0, 0, 0);
    f32x4 d1b = MFMA16(aB.v, B1[1].v, bcast4(b1v1), 0, 0, 0);
    if (quad < 2) {
#pragma unroll
      for (int r = 0; r < 4; ++r)
        p_write(ds, fmaxf(fmaxf(d0a[r], d0b[r]), 0.f), fmaxf(fmaxf(d1a[r], d1b[r]), 0.f), r);
    }
  };
  auto ld_P = [&](int s) -> FragU {
    FragU a; a.q = *(const uint4*)&sm.P[pIdx(s, n & 7, quad ^ (n & 3))]; return a;
  };
  auto c2init = [&]() -> Acc4 {
    Acc4 c;
#pragma unroll
    for (int ct = 0; ct < 4; ++ct) c.a[ct] = bcast4(b2v[ct]);
    return c;
  };
  auto c2acc = [&](Acc4& c, FragU a, int dw) {
#pragma unroll
    for (int ct = 0; ct < 4; ++ct) c.a[ct] = MFMA16(a.v, B2[dw][ct].v, c.a[ct], 0, 0, 0);
  };
  auto c2store = [&](Acc4& c, int ds) {
    if (quad < 2) {
#pragma unroll
      for (int r = 0; r < 4; ++r) {
        int veh = quad * 4 + r;
        float m0 = fmaxf(c.a[0][r], 0.f), m1 = fmaxf(c.a[1][r], 0.f);
        float m2 = fmaxf(c.a[2][r], 0.f), m3 = fmaxf(c.a[3][r], 0.f);
        uint2 w2; w2.x = pkbf(m0, m1); w2.y = pkbf(m2, m3);
        *(uint2*)&sm.O2[oIdx(ds, veh, (n >> 1) ^ (veh & 7)) + (n & 1) * 4] = w2;
      }
    }
  };
  auto ld_O = [&](int s, int hf) -> uint4 {
    return *(const uint4*)&sm.O2[oIdx(s, n & 7, (hf * 4 + quad) ^ (n & 7))];
  };
  auto ld_O_max = [&](int pa, int pb, int hf) -> FragU {
    FragU a;
    uint4 qa = ld_O(pa, hf);
    if (pb >= 0) qa = maxq(qa, ld_O(pb, hf));
    a.q = qa; return a;
  };

  // W1/W3 job: r0 -> j0 -> jp0 for target step tp (slot sp, parity parp).
  // tm24p/tm20p are (tp mod 24)/(tp mod 20).
  auto helper_front = [&](int tp, int tm24p, int tm20p, int sp, int parp) {
    conv1_pair(tp, 1, 0, tp + 1, 0, 0, 24 + sp);          // r0 -> local
    FragU pA = ld_P(w24(tm24p + 2)), pB = ld_P(w24(tm24p + 4));
    Acc4 c = c2init();
    c2acc(c, pA, 1); c2acc(c, pB, 2);
    FragU fr0 = ld_P(24 + sp);
    c2acc(c, fr0, 0);
    c2store(c, 20 + sp);                                   // j0 -> local
    int a2 = w20(tm20p + 2);
    FragU h0 = ld_O_max(20 + sp, a2, 0), h1 = ld_O_max(20 + sp, a2, 1);
    f32x4 q0 = MFMA16(Bd[0].v, h0.v, bcast4(0.f), 0, 0, 0);
    f32x4 q1 = MFMA16(Bd[1].v, h1.v, bcast4(0.f), 0, 0, 0);
    *(f32x4*)&sm.jpacc[parp][sp][0][lane][0] = q0 + q1;
  };

  __syncthreads();

  // ---------------- phase 1: P ring init g=2..21 ----------------
#pragma unroll
  for (int i = 0; i < 5; ++i) {
    int g = 2 + wid + 4 * i;
    conv1_pair(g, 0, 0, g + 1, 0, 0, g);
  }
  __syncthreads();

  // ---------------- phase 2: O2 ring init a=2..17 ----------------
#pragma unroll
  for (int i = 0; i < 4; ++i) {
    int a = 2 + wid + 4 * i;
    Acc4 c = c2init();
    c2acc(c, ld_P(a), 0);
    c2acc(c, ld_P(a + 2), 1);
    c2acc(c, ld_P(a + 4), 2);
    c2store(c, a);
  }
  __syncthreads();

  // rolling x-columns for the chain (u = 21..24)
  uint32_t c21 = 0, c22 = 0, c23 = 0, c24 = 0;
  if (wid == 0) { c21 = Xld(21); c22 = Xld(22); c23 = Xld(23); c24 = Xld(24); }

  // ---------------- main loop: blocks of 4 steps ----------------
  const int nblk = nt >> 2;
  int tmP = 20, tmO = 16;             // (4*B) mod {24,20} for B = -1
  for (int B = -1; B < nblk; ++B) {
    const int par = B & 1;
    const int parp = (B + 1) & 1;

    if (wid == 0) {
      if (B >= 0) {
        const int tXc = ((B << 2) + PAST) & 31;
#pragma unroll
        for (int s = 0; s < 4; ++s) {
          const int g18 = w24(tmP + 18 + s), g20 = w24(tmP + 20 + s), g22 = w24(tmP + 22 + s);
          const int a12 = w20(tmO + 12 + s), a14 = w20(tmO + 14 + s);
          const int a16 = w20(tmO + 16 + s), a18 = w20(tmO + 18 + s);
          // early independent loads
          FragU p18 = ld_P(g18), p20 = ld_P(g20);
          FragU j3a = ld_O_max(a12, a14, 0), j3b = ld_O_max(a12, a14, 1);
          uint4 q8h0 = ld_O(a16, 0), q8h1 = ld_O(a16, 1);
          f32x4 jh1 = *(const f32x4*)&sm.jpacc[par][s][0][lane][0];
          f32x4 jh2 = *(const f32x4*)&sm.jpacc[par][s][1][lane][0];
          float2 ln; ln.x = 0.f; ln.y = 0.f;
          if (lane < 8) ln = sm.leadsl[par][s][lane];
          // jp3 (early) — carries the dense bias once
          f32x4 zc0 = MFMA16(Bd[6].v, j3a.v, dbias, 0, 0, 0);
          f32x4 zc1 = MFMA16(Bd[7].v, j3b.v, bcast4(0.f), 0, 0, 0);
          // conv2 old terms (early-issue)
          Acc4 c9 = c2init(); c2acc(c9, p18, 0); c2acc(c9, p20, 1);
          Acc4 cB = c2init(); c2acc(cB, p20, 0);
          // fresh conv1 rows 11 (centers t+22,t+23) and 12 (center t+24, padR)
          FragU aA = mkfrag(c21, c22, c23);
          FragU aB = mkfrag(c22, c23, c24);
          FragU aC = mkfrag(c23, c24, 0u);
          f32x4 d0a = MFMA16(aA.v, B1[0].v, bcast4(b1v0), 0, 0, 0);
          f32x4 d0b = MFMA16(aB.v, B1[0].v, bcast4(b1v0), 0, 0, 0);
          f32x4 d1a = MFMA16(aA.v, B1[1].v, bcast4(b1v1), 0, 0, 0);
          f32x4 d1b = MFMA16(aB.v, B1[1].v, bcast4(b1v1), 0, 0, 0);
          f32x4 e0 = MFMA16(aC.v, B1[0].v, bcast4(b1v0), 0, 0, 0);
          f32x4 e1 = MFMA16(aC.v, B1[1].v, bcast4(b1v1), 0, 0, 0);
          if (quad < 2) {
#pragma unroll
            for (int r = 0; r < 4; ++r) {
              p_write(g22, fmaxf(fmaxf(d0a[r], d0b[r]), 0.f),
                      fmaxf(fmaxf(d1a[r], d1b[r]), 0.f), r);
              p_write(28, fmaxf(e0[r], 0.f), fmaxf(e1[r], 0.f), r);
            }
          }
          FragU fr11 = ld_P(g22), fr12 = ld_P(28);          // RT1
          c2acc(c9, fr11, 2); c2store(c9, a18);             // j9 -> ring
          c2acc(cB, fr11, 1); c2acc(cB, fr12, 2);
          c2store(cB, 24);                                  // j10 -> local
          FragU j4h0, j4h1, j5h0, j5h1;                     // RT2
          j4h0.q = maxq(q8h0, ld_O(a18, 0));
          j4h1.q = maxq(q8h1, ld_O(a18, 1));
          j5h0.q = ld_O(24, 0);
          j5h1.q = ld_O(24, 1);
          f32x4 za = MFMA16(Bd[8].v, j4h0.v, zc0, 0, 0, 0);
          f32x4 zb = MFMA16(Bd[9].v, j4h1.v, zc1, 0, 0, 0);
          za = MFMA16(Bd[10].v, j5h0.v, za, 0, 0, 0);
          zb = MFMA16(Bd[11].v, j5h1.v, zb, 0, 0, 0);
          // epilogue
          f32x4 tot = (za + zb) + (jh1 + jh2);
          float p = fmaxf(tot[0], 0.f) * w1r[0] + fmaxf(tot[1], 0.f) * w1r[1] +
                    fmaxf(tot[2], 0.f) * w1r[2] + fmaxf(tot[3], 0.f) * w1r[3];
          p += __shfl_xor(p, 16, 64);
          p += __shfl_xor(p, 32, 64);
          uint32_t ccx = 0, ccy = 0;
          if (lane < 8) {
            float accv = 10.f * (p + bd1v) - 6.f;           // (MAXA-MINA)*x + MINA
            float np_s = pos_s + 0.02f * spd_s;
            float nsp = spd_s * 40.f + 0.1f * accv;
            pos_s = np_s; spd_s = nsp * 0.025f;
            float2 o2v; o2v.x = np_s * 200.f; o2v.y = nsp;
            sm.obuf[par][s][lane] = o2v;
            float x0 = ln.x * 0.005f - np_s;                // column u = t+25
            uint32_t hi = f2bf(x0);
            uint32_t lo = f2bf(x0 - bf2f(hi));
            ccx = hi | (f2bf(spd_s) << 16);
            ccy = f2bf(ln.y * 0.025f) | (lo << 16);
            uint2 cc; cc.x = ccx; cc.y = ccy;
            *(uint2*)&sm.Xcol[lane][(tXc + s) & 31][0] = cc;
          }
          uint32_t sx = (uint32_t)__shfl((int)ccx, n & 7, 64);
          uint32_t sy = (uint32_t)__shfl((int)ccy, n & 7, 64);
          uint32_t colnew = (quad & 1) ? sy : sx;
          c21 = c22; c22 = c23; c23 = c24; c24 = colnew;
        }
      }
    } else if (wid == 1 || wid == 3) {
      // W1: next-block steps +4,+5 ; W3: +6,+7
      int e0i = (wid == 1) ? 0 : 2;
#pragma unroll
      for (int k = 0; k < 2; ++k) {
        int e = e0i + k;
        int tp = ((B + 1) << 2) + e;
        if (tp < nt)
          helper_front(tp, w24(tmP + 4 + e), w20(tmO + 4 + e), e, parp);
      }
    } else {
      // W2: jp1/jp2 for next-block steps, lead prefetch, obuf flush
#pragma unroll
      for (int e = 0; e < 4; ++e) {
        int tp = ((B + 1) << 2) + e;
        if (tp < nt) {
          int a4 = w20(tmO + 8 + e), a6 = w20(tmO + 10 + e);
          int a8 = w20(tmO + 12 + e), a10 = w20(tmO + 14 + e);
          FragU h;
          f32x4 q0 = bcast4(0.f), q1 = bcast4(0.f);
          h = ld_O_max(a4, a6, 0);  q0 = MFMA16(Bd[2].v, h.v, q0, 0, 0, 0);
          h = ld_O_max(a4, a6, 1);  q1 = MFMA16(Bd[3].v, h.v, q1, 0, 0, 0);
          h = ld_O_max(a8, a10, 0); q0 = MFMA16(Bd[4].v, h.v, q0, 0, 0, 0);
          h = ld_O_max(a8, a10, 1); q1 = MFMA16(Bd[5].v, h.v, q1, 0, 0, 0);
          *(f32x4*)&sm.jpacc[parp][e][1][lane][0] = q0 + q1;
        }
      }
      if (lane < 32) {
        int e = lane >> 3, veh = lane & 7;
        int tp = ((B + 1) << 2) + e;
        if (tp < nt) {
          int ui = tp + PAST; if (ui > ntw - 1) ui = ntw - 1;
          float2 l = *(const float2*)(lead_states + ((size_t)(vbase + veh) * ntw + ui) * 2);
          sm.leadsl[parp][e][veh] = l;
        }
        if (B >= 1) {
          int t_out = ((B - 1) << 2) + e;
          float2 d = sm.obuf[(B - 1) & 1][e][veh];
          *(float2*)(out + ((size_t)(vbase + veh) * nt + t_out) * 2) = d;
        }
      }
    }
    __syncthreads();

    tmP += 4; if (tmP >= 24) tmP -= 24;
    tmO += 4; if (tmO >= 20) tmO -= 20;
  }

  // final flush: last block's outputs
  if (wid == 2 && lane < 32) {
    int e = lane >> 3, veh = lane & 7;
    int t_out = ((nblk - 1) << 2) + e;
    float2 d = sm.obuf[(nblk - 1) & 1][e][veh];
    *(float2*)(out + ((size_t)(vbase + veh) * nt + t_out) * 2) = d;
  }
}

extern "C" void kernel_launch(void* const* d_in, const int* in_sizes, int n_in,
                              void* d_out, int out_size, void* d_ws, size_t ws_size,
                              hipStream_t stream) {
  const float* lead = (const float*)d_in[0];
  const float* cur  = (const float*)d_in[1];
  // d_in[2] = mask (unused by reference)
  const float* c1w = (const float*)d_in[3];
  const float* c1b = (const float*)d_in[4];
  const float* c2w = (const float*)d_in[5];
  const float* c2b = (const float*)d_in[6];
  const float* d2w = (const float*)d_in[7];
  const float* d2b = (const float*)d_in[8];
  const float* d1w = (const float*)d_in[9];
  const float* d1b = (const float*)d_in[10];
  float* out = (float*)d_out;

  int nveh = in_sizes[1] / (PAST * 2);   // 4096
  int ntw  = in_sizes[2] / nveh;         // nt + PAST - 1
  int nt   = ntw - PAST + 1;             // 256
  int nblocks = nveh / 8;                // 512 WGs x 4 waves

  rnncf_kernel<<<nblocks, 256, 0, stream>>>(lead, cur, c1w, c1b, c2w, c2b,
                                            d2w, d2b, d1w, d1b, out, nt, ntw);
}